// Round 16
// baseline (730.190 us; speedup 1.0000x reference)
//
#include <hip/hip_runtime.h>
#include <math.h>

// ---- static config (matches reference) ----
#define F 128
#define KRBF 32
#define TINTER 3
#define RMAX 5.0f
#define INV_AVG (1.0f/16.0f)
#define GAMMA 40.96f               // (KRBF/RMAX)^2
#define RSQRT_DH 0.17677669529663689f  // 1/sqrt(32)
#define PI_F 3.14159265358979323846f
#define TAB_N 2048                 // w(r) interpolation table entries over [0, RMAX]
#define APITCH 68                  // LDS A-tile pitch in dwords (16B-aligned rows)
#define SCB 256                    // scan block size

__device__ __forceinline__ float silu_f(float x) { return x / (1.0f + expf(-x)); }
__device__ __forceinline__ int deg_of(int c) { return (c == 0) ? 0 : (c < 4) ? 1 : (c < 9) ? 2 : 3; }

// bf16x2 pack/unpack: packed word = (elem0) | (elem1 << 16), RNE rounding
__device__ __forceinline__ unsigned int pk_bf2(float lo, float hi) {
    unsigned int a = __float_as_uint(lo), b = __float_as_uint(hi);
    unsigned int ar = (a + 0x7fffu + ((a >> 16) & 1u)) >> 16;
    unsigned int br = (b + 0x7fffu + ((b >> 16) & 1u)) >> 16;
    return ar | (br << 16);
}
__device__ __forceinline__ float up_lo(unsigned int u) { return __uint_as_float(u << 16); }
__device__ __forceinline__ float up_hi(unsigned int u) { return __uint_as_float(u & 0xffff0000u); }

typedef short s16x8 __attribute__((ext_vector_type(8)));
typedef float f32x4 __attribute__((ext_vector_type(4)));
typedef float f32x2 __attribute__((ext_vector_type(2)));
union FragU { uint4 u; s16x8 s; };

__device__ __forceinline__ f32x2 up2(unsigned int u) {
    f32x2 r; r.x = up_lo(u); r.y = up_hi(u); return r;
}

// 16-lane (head-group) sum via DPP — pure VALU, no LDS-pipe bpermute.
__device__ __forceinline__ float red16_dpp(float p) {
    p += __uint_as_float((unsigned)__builtin_amdgcn_update_dpp(
        0, (int)__float_as_uint(p), 0xB1, 0xF, 0xF, true));   // quad_perm [1,0,3,2]
    p += __uint_as_float((unsigned)__builtin_amdgcn_update_dpp(
        0, (int)__float_as_uint(p), 0x4E, 0xF, 0xF, true));   // quad_perm [2,3,0,1]
    p += __uint_as_float((unsigned)__builtin_amdgcn_update_dpp(
        0, (int)__float_as_uint(p), 0x124, 0xF, 0xF, true));  // row_ror:4
    p += __uint_as_float((unsigned)__builtin_amdgcn_update_dpp(
        0, (int)__float_as_uint(p), 0x128, 0xF, 0xF, true));  // row_ror:8
    return p;
}

// ---------------------------------------------------------------------------
// CSR build: count -> parallel 3-phase scan -> scatter
// ---------------------------------------------------------------------------
__global__ void count_kernel(const int* __restrict__ rcv, int* __restrict__ cnt, int E)
{
    int e = blockIdx.x * blockDim.x + threadIdx.x;
    if (e < E) atomicAdd(&cnt[rcv[e]], 1);
}

__global__ __launch_bounds__(SCB) void scan_part_kernel(const int* __restrict__ cnt,
                                                        int* __restrict__ off,
                                                        int* __restrict__ bsum, int N)
{
    __shared__ int s[SCB];
    int tid = threadIdx.x;
    int i = blockIdx.x * SCB + tid;
    int v = (i < N) ? cnt[i] : 0;
    s[tid] = v;
    __syncthreads();
    for (int st = 1; st < SCB; st <<= 1) {
        int t = (tid >= st) ? s[tid - st] : 0;
        __syncthreads();
        s[tid] += t;
        __syncthreads();
    }
    if (i < N) off[i] = s[tid] - v;
    if (tid == SCB - 1) bsum[blockIdx.x] = s[tid];
}

__global__ __launch_bounds__(1024) void scan_mid_kernel(const int* __restrict__ bsum,
                                                        int* __restrict__ boff,
                                                        int* __restrict__ off, int N, int nb)
{
    __shared__ int s[1024];
    int tid = threadIdx.x;
    int v = (tid < nb) ? bsum[tid] : 0;
    s[tid] = v;
    __syncthreads();
    for (int st = 1; st < 1024; st <<= 1) {
        int t = (tid >= st) ? s[tid - st] : 0;
        __syncthreads();
        s[tid] += t;
        __syncthreads();
    }
    if (tid < nb) boff[tid] = s[tid] - v;
    if (tid == 1023) off[N] = s[1023];
}

__global__ void scan_add_kernel(int* __restrict__ off, int* __restrict__ cur,
                                const int* __restrict__ boff, int N)
{
    int i = blockIdx.x * blockDim.x + threadIdx.x;
    if (i < N) {
        int v = off[i] + boff[i / SCB];
        off[i] = v; cur[i] = v;
    }
}

__global__ void scatter_kernel(const int* __restrict__ rcv, int* __restrict__ cur,
                               int* __restrict__ elist, int E)
{
    int e = blockIdx.x * blockDim.x + threadIdx.x;
    if (e < E) {
        int p = atomicAdd(&cur[rcv[e]], 1);
        elist[p] = e;
    }
}

// ---------------------------------------------------------------------------
// Fused edge geometry in CSR order. edata[ei] = {s, r, C, pad | dd0..3}
// ---------------------------------------------------------------------------
__global__ void edge_geom_csr_kernel(const int* __restrict__ elist,
                                     const float* __restrict__ pos,
                                     const int* __restrict__ snd,
                                     const int* __restrict__ rcv,
                                     int* __restrict__ sp, int* __restrict__ rcvp,
                                     float* __restrict__ Cb,
                                     float4* __restrict__ edata,
                                     float* __restrict__ Yp, int E)
{
    int ei = blockIdx.x * blockDim.x + threadIdx.x;
    if (ei >= E) return;
    int e = elist[ei];
    int s = snd[e], rc = rcv[e];
    sp[ei] = s; rcvp[ei] = rc;
    float vx = pos[rc * 3 + 0] - pos[s * 3 + 0];
    float vy = pos[rc * 3 + 1] - pos[s * 3 + 1];
    float vz = pos[rc * 3 + 2] - pos[s * 3 + 2];
    float r = sqrtf(vx * vx + vy * vy + vz * vz);
    float rinv = 1.0f / fmaxf(r, 1e-9f);
    float x = vx * rinv, y = vy * rinv, z = vz * rinv;
    float x2 = x * x, y2 = y * y, z2 = z * z;
    const float s3 = 1.7320508075688772f, s5 = 2.23606797749979f, s15 = 3.872983346207417f;
    const float s70 = 8.366600265340756f, s105 = 10.246950765959598f;
    const float s42 = 6.48074069840786f, s7 = 2.6457513110645907f;
    float Y[16];
    Y[0] = 1.0f;
    Y[1] = s3 * x; Y[2] = s3 * y; Y[3] = s3 * z;
    Y[4] = s15 * x * y; Y[5] = s15 * y * z; Y[6] = 0.5f * s5 * (3.0f * z2 - 1.0f);
    Y[7] = s15 * x * z; Y[8] = 0.5f * s15 * (x2 - y2);
    Y[9]  = 0.25f * s70 * y * (3.0f * x2 - y2);
    Y[10] = s105 * x * y * z;
    Y[11] = 0.25f * s42 * y * (5.0f * z2 - 1.0f);
    Y[12] = 0.5f * s7 * z * (5.0f * z2 - 3.0f);
    Y[13] = 0.25f * s42 * x * (5.0f * z2 - 1.0f);
    Y[14] = 0.5f * s105 * z * (x2 - y2);
    Y[15] = 0.25f * s70 * x * (x2 - 3.0f * y2);
    float C = (r < RMAX) ? 0.5f * (cosf(PI_F * r / RMAX) + 1.0f) : 0.0f;
    Cb[ei] = C;
    edata[2 * ei] = make_float4(__int_as_float(s), r, C, 0.0f);
    #pragma unroll
    for (int c = 0; c < 16; c++) Yp[(size_t)ei * 16 + c] = Y[c];
}

// ---------------------------------------------------------------------------
// ev0[n] = sum_{ei in CSR(n)} Yp[ei]*C[ei] * INV_AVG
// ---------------------------------------------------------------------------
__global__ void ev0_kernel(const int* __restrict__ off,
                           const float* __restrict__ Yp, const float* __restrict__ Cb,
                           float* __restrict__ ev, int N)
{
    int n = blockIdx.x * 16 + (threadIdx.x >> 4);
    int c = threadIdx.x & 15;
    if (n >= N) return;
    float acc = 0.0f;
    int e0 = off[n], e1 = off[n + 1];
    for (int ei = e0; ei < e1; ei++)
        acc += Yp[(size_t)ei * 16 + c] * Cb[ei];
    ev[n * 16 + c] = acc * INV_AVG;
}

// ---------------------------------------------------------------------------
// f = embed[species]
// ---------------------------------------------------------------------------
__global__ void embed_kernel(const int* __restrict__ species,
                             const float* __restrict__ embed,
                             float* __restrict__ f, int N)
{
    int n = blockIdx.x;
    if (n >= N) return;
    int j = threadIdx.x;
    f[n * F + j] = embed[species[n] * F + j];
}

// ---------------------------------------------------------------------------
// Pack 18 128x128 fp32 weight matrices into MFMA B-operand bf16 layout.
// ---------------------------------------------------------------------------
__global__ void pack_w_kernel(const float* __restrict__ Wq, const float* __restrict__ Wk,
                              const float* __restrict__ Wv, const float* __restrict__ Wo,
                              const float* __restrict__ Wq2, const float* __restrict__ Wk2,
                              unsigned int* __restrict__ Wpk)
{
    int tid = blockIdx.x * blockDim.x + threadIdx.x;
    if (tid >= 18 * 8192) return;
    int mat = tid >> 13;
    int rem = tid & 8191;
    int iw = rem & 3;
    int n = (rem >> 2) & 15;
    int quad = (rem >> 6) & 3;
    int kb = (rem >> 8) & 3;
    int ct = rem >> 10;
    const float* fam = (mat < 3) ? Wq : (mat < 6) ? Wk : (mat < 9) ? Wv
                     : (mat < 12) ? Wo : (mat < 15) ? Wq2 : Wk2;
    const float* src = fam + (size_t)(mat % 3) * F * F;
    int k = kb * 32 + quad * 8 + iw * 2;
    int col = ct * 16 + n;
    Wpk[tid] = pk_bf2(src[k * F + col], src[(k + 1) * F + col]);
}

// Pack the 7 exchange/readout 128x128 submatrices in one dispatch
__global__ void pack_ex_kernel(const float* __restrict__ Wex1, const float* __restrict__ Wex2,
                               const float* __restrict__ Wo1, unsigned int* __restrict__ Wpk2)
{
    int tid = blockIdx.x * blockDim.x + threadIdx.x;
    if (tid >= 7 * 8192) return;
    int mat = tid >> 13;
    int rem = tid & 8191;
    int iw = rem & 3;
    int n = (rem >> 2) & 15;
    int quad = (rem >> 6) & 3;
    int kb = (rem >> 8) & 3;
    int ct = rem >> 10;
    const float* src; int stride;
    if (mat < 3)      { src = Wex1 + (size_t)mat * (F + 4) * F; stride = F; }
    else if (mat < 6) { src = Wex2 + (size_t)(mat - 3) * F * (F + 4); stride = F + 4; }
    else              { src = Wo1; stride = F; }
    int k = kb * 32 + quad * 8 + iw * 2;
    int col = ct * 16 + n;
    Wpk2[tid] = pk_bf2(src[(size_t)k * stride + col], src[(size_t)(k + 1) * stride + col]);
}

// ---------------------------------------------------------------------------
// Build paired bf16 w(r) table directly (entry i holds w_i and w_{i+1})
// ---------------------------------------------------------------------------
__global__ __launch_bounds__(256) void build_table_kernel(
    const float* __restrict__ Wrbf1_all, const float* __restrict__ brbf1_all,
    const float* __restrict__ Wrbf2_all, unsigned int* __restrict__ tab2w)
{
    int wave = threadIdx.x >> 6;
    int lane = threadIdx.x & 63;
    int idx = blockIdx.x * 4 + wave;
    int t = blockIdx.y;
    const float* W1 = Wrbf1_all + (size_t)t * KRBF * F;
    const float* b1 = brbf1_all + (size_t)t * F;
    const float* W2 = Wrbf2_all + (size_t)t * F * F;
    float r = idx * (RMAX / (TAB_N - 1));
    __shared__ float sR[4][KRBF];
    __shared__ float sH[4][F];
    if (lane < KRBF) {
        float mu = lane * (RMAX / (KRBF - 1));
        float d = r - mu;
        sR[wave][lane] = expf(-GAMMA * d * d);
    }
    __syncthreads();
    float h0 = b1[lane], h1 = b1[lane + 64];
    #pragma unroll
    for (int kk = 0; kk < KRBF; kk++) {
        float rv = sR[wave][kk];
        h0 += rv * W1[kk * F + lane];
        h1 += rv * W1[kk * F + lane + 64];
    }
    sH[wave][lane] = silu_f(h0);
    sH[wave][lane + 64] = silu_f(h1);
    __syncthreads();
    float w0 = 0.0f, w1 = 0.0f;
    for (int i = 0; i < F; i++) {
        float hv = sH[wave][i];
        w0 += hv * W2[i * F + 2 * lane];
        w1 += hv * W2[i * F + 2 * lane + 1];
    }
    unsigned int w = pk_bf2(w0, w1);
    size_t base = ((size_t)t * TAB_N + idx) * 64 + lane;   // uint2 index
    tab2w[base * 2] = w;
    if (idx > 0) tab2w[(base - 64) * 2 + 1] = w;
    if (idx == TAB_N - 1) tab2w[base * 2 + 1] = w;
}

// ---------------------------------------------------------------------------
// edata[ei].dd = deg_reduce(ev[sp[ei]] * ev[rcvp[ei]])  (second 16B half)
// ---------------------------------------------------------------------------
__global__ void dd_kernel(const int* __restrict__ sp, const int* __restrict__ rcvp,
                          const float* __restrict__ ev, float4* __restrict__ edata, int E)
{
    int ei = blockIdx.x * blockDim.x + threadIdx.x;
    if (ei >= E) return;
    int s = sp[ei], rc = rcvp[ei];
    const float4* a = (const float4*)(ev + (size_t)s * 16);
    const float4* b = (const float4*)(ev + (size_t)rc * 16);
    float4 a0 = a[0], a1 = a[1], a2 = a[2], a3 = a[3];
    float4 b0 = b[0], b1 = b[1], b2 = b[2], b3 = b[3];
    float d0 = a0.x * b0.x;
    float d1 = a0.y * b0.y + a0.z * b0.z + a0.w * b0.w;
    float d2 = a1.x * b1.x + a1.y * b1.y + a1.z * b1.z + a1.w * b1.w + a2.x * b2.x;
    float d3 = a2.y * b2.y + a2.z * b2.z + a2.w * b2.w
             + a3.x * b3.x + a3.y * b3.y + a3.z * b3.z + a3.w * b3.w;
    edata[2 * ei + 1] = make_float4(d0, d1, d2, d3);
}

// ---------------------------------------------------------------------------
// MFMA node GEMM (t=0 qkv): 512 threads, 8 waves = (row-group, ct-half).
// ---------------------------------------------------------------------------
__global__ __launch_bounds__(512) void node_gemm_mfma_kernel(
    const float* __restrict__ A,
    const unsigned int* __restrict__ B0, const unsigned int* __restrict__ B1,
    const unsigned int* __restrict__ B2,
    float* __restrict__ out0, unsigned int* __restrict__ out1,
    int N)
{
    __shared__ unsigned int sA[64 * APITCH];
    int tid = threadIdx.x;
    int n0 = blockIdx.x * 64;
    #pragma unroll
    for (int rep = 0; rep < 8; rep++) {
        int idx = rep * 512 + tid;
        int node = idx >> 6, jj = idx & 63;
        int n = n0 + node;
        float2 v = (n < N) ? ((const float2*)A)[(size_t)n * 64 + jj] : make_float2(0.f, 0.f);
        sA[node * APITCH + jj] = pk_bf2(v.x, v.y);
    }
    __syncthreads();
    int wave = tid >> 6, lane = tid & 63;
    int rg = wave & 3, ch = wave >> 2;
    int quad = lane >> 4, col = lane & 15;
    int mrow = rg * 16 + col;
    s16x8 af[4];
    #pragma unroll
    for (int kb = 0; kb < 4; kb++) {
        FragU fu;
        fu.u = *(const uint4*)&sA[mrow * APITCH + kb * 16 + quad * 4];
        af[kb] = fu.s;
    }
    for (int m = 0; m < 3; m++) {
        const unsigned int* B = (m == 0) ? B0 : (m == 1) ? B1 : B2;
        for (int c2 = 0; c2 < 4; c2++) {
            int ct = ch * 4 + c2;
            f32x4 acc = {0.f, 0.f, 0.f, 0.f};
            #pragma unroll
            for (int kb = 0; kb < 4; kb++) {
                FragU bu;
                bu.u = *(const uint4*)&B[(size_t)((ct * 16 + kb * 4 + quad) * 16 + col) * 4];
                acc = __builtin_amdgcn_mfma_f32_16x16x32_bf16(af[kb], bu.s, acc, 0, 0, 0);
            }
            if (m == 0) {
                #pragma unroll
                for (int r = 0; r < 4; r++) {
                    int n = n0 + rg * 16 + quad * 4 + r;
                    if (n < N) out0[(size_t)n * F + ct * 16 + col] = acc[r];
                }
            } else {
                #pragma unroll
                for (int r = 0; r < 4; r++) {
                    float other = __shfl_xor(acc[r], 1, 64);
                    if (!(lane & 1)) {
                        int n = n0 + rg * 16 + quad * 4 + r;
                        if (n < N) {
                            size_t base = (size_t)n * 64 + ct * 8 + (col >> 1);
                            out1[base * 2 + (m - 1)] = pk_bf2(acc[r], other);
                        }
                    }
                }
            }
        }
    }
}

// ---------------------------------------------------------------------------
// Fused: f += agg@Wo ; q = f@Wq2 (fp32); k2 = f@Wk2 (bf16). 512 thr, ct-split.
// agg may alias qout (input fully staged before any write).
// ---------------------------------------------------------------------------
__global__ __launch_bounds__(512) void fused_o_qk_kernel(
    const float* __restrict__ agg,
    const unsigned int* __restrict__ Bo, const unsigned int* __restrict__ Bq2,
    const unsigned int* __restrict__ Bk2,
    float* __restrict__ f, float* __restrict__ qout, unsigned int* __restrict__ k16p,
    int N)
{
    __shared__ unsigned int sA[64 * APITCH];
    int tid = threadIdx.x;
    int n0 = blockIdx.x * 64;
    #pragma unroll
    for (int rep = 0; rep < 8; rep++) {
        int idx = rep * 512 + tid;
        int node = idx >> 6, jj = idx & 63;
        int n = n0 + node;
        float2 v = (n < N) ? ((const float2*)agg)[(size_t)n * 64 + jj] : make_float2(0.f, 0.f);
        sA[node * APITCH + jj] = pk_bf2(v.x, v.y);
    }
    __syncthreads();
    int wave = tid >> 6, lane = tid & 63;
    int rg = wave & 3, ch = wave >> 2;
    int quad = lane >> 4, col = lane & 15;
    int mrow = rg * 16 + col;
    s16x8 af[4];
    #pragma unroll
    for (int kb = 0; kb < 4; kb++) {
        FragU fu;
        fu.u = *(const uint4*)&sA[mrow * APITCH + kb * 16 + quad * 4];
        af[kb] = fu.s;
    }
    __syncthreads();
    // GEMM1: f_new = f + agg@Wo -> write f (fp32) + pack f_new into sA (bf16)
    for (int c2 = 0; c2 < 4; c2++) {
        int ct = ch * 4 + c2;
        f32x4 acc = {0.f, 0.f, 0.f, 0.f};
        #pragma unroll
        for (int kb = 0; kb < 4; kb++) {
            FragU bu;
            bu.u = *(const uint4*)&Bo[(size_t)((ct * 16 + kb * 4 + quad) * 16 + col) * 4];
            acc = __builtin_amdgcn_mfma_f32_16x16x32_bf16(af[kb], bu.s, acc, 0, 0, 0);
        }
        #pragma unroll
        for (int r = 0; r < 4; r++) {
            int node = rg * 16 + quad * 4 + r;
            int n = n0 + node;
            float fx = 0.0f;
            if (n < N) {
                size_t ix = (size_t)n * F + ct * 16 + col;
                fx = f[ix] + acc[r];
                f[ix] = fx;
            }
            float other = __shfl_xor(fx, 1, 64);
            if (!(lane & 1)) sA[node * APITCH + ct * 8 + (col >> 1)] = pk_bf2(fx, other);
        }
    }
    __syncthreads();
    s16x8 a2[4];
    #pragma unroll
    for (int kb = 0; kb < 4; kb++) {
        FragU fu;
        fu.u = *(const uint4*)&sA[mrow * APITCH + kb * 16 + quad * 4];
        a2[kb] = fu.s;
    }
    // GEMM2a: q = f_new @ Wq2 (fp32)
    for (int c2 = 0; c2 < 4; c2++) {
        int ct = ch * 4 + c2;
        f32x4 acc = {0.f, 0.f, 0.f, 0.f};
        #pragma unroll
        for (int kb = 0; kb < 4; kb++) {
            FragU bu;
            bu.u = *(const uint4*)&Bq2[(size_t)((ct * 16 + kb * 4 + quad) * 16 + col) * 4];
            acc = __builtin_amdgcn_mfma_f32_16x16x32_bf16(a2[kb], bu.s, acc, 0, 0, 0);
        }
        #pragma unroll
        for (int r = 0; r < 4; r++) {
            int n = n0 + rg * 16 + quad * 4 + r;
            if (n < N) qout[(size_t)n * F + ct * 16 + col] = acc[r];
        }
    }
    // GEMM2b: k2 = f_new @ Wk2 (bf16 packed)
    for (int c2 = 0; c2 < 4; c2++) {
        int ct = ch * 4 + c2;
        f32x4 acc = {0.f, 0.f, 0.f, 0.f};
        #pragma unroll
        for (int kb = 0; kb < 4; kb++) {
            FragU bu;
            bu.u = *(const uint4*)&Bk2[(size_t)((ct * 16 + kb * 4 + quad) * 16 + col) * 4];
            acc = __builtin_amdgcn_mfma_f32_16x16x32_bf16(a2[kb], bu.s, acc, 0, 0, 0);
        }
        #pragma unroll
        for (int r = 0; r < 4; r++) {
            float other = __shfl_xor(acc[r], 1, 64);
            if (!(lane & 1)) {
                int n = n0 + rg * 16 + quad * 4 + r;
                if (n < N) k16p[(size_t)n * 64 + ct * 8 + (col >> 1)] = pk_bf2(acc[r], other);
            }
        }
    }
}

// ---------------------------------------------------------------------------
// Per-edge alpha (q pre-scaled). Table row base scalarized; DPP reduce.
// ---------------------------------------------------------------------------
__device__ __forceinline__ float edge_alpha(
    int lane, f32x2 qq, f32x2 wd0, f32x2 wd1, f32x2 wd2, f32x2 wd3,
    const uint2* __restrict__ tab2, float rr, float4 dd, unsigned int ku)
{
    float u = rr * ((float)(TAB_N - 1) / RMAX);
    int i0 = (int)u;
    i0 = (i0 > TAB_N - 2) ? (TAB_N - 2) : i0;
    float fr = u - (float)i0;
    int i0s = __builtin_amdgcn_readfirstlane(i0);
    uint2 tp = (tab2 + (size_t)i0s * 64)[lane];
    f32x2 a = up2(tp.x), b = up2(tp.y);
    f32x2 fr2 = {fr, fr};
    f32x2 w = a + fr2 * (b - a);
    f32x2 d0 = {dd.x, dd.x}, d1 = {dd.y, dd.y}, d2 = {dd.z, dd.z}, d3 = {dd.w, dd.w};
    w = w + d0 * wd0 + d1 * wd1 + d2 * wd2 + d3 * wd3;
    f32x2 p2 = qq * w * up2(ku);
    return red16_dpp(p2.x + p2.y);
}

// ---------------------------------------------------------------------------
// Node-centric fused edge pass; 8-deep gather pipeline: sender indices are
// read first (dword sweep), all 8 kv/k gathers issued, then edata re-read
// (L2-hot) in the consume loop.
// ---------------------------------------------------------------------------
__global__ __launch_bounds__(256) void edge_pass_node_kernel(
    const int* __restrict__ off, const float4* __restrict__ edata,
    const float* __restrict__ Yp,
    const float* __restrict__ qbuf,
    const uint2* __restrict__ kv16, const unsigned int* __restrict__ k16p,
    const uint2* __restrict__ tab2, const float* __restrict__ Wdeg_t,
    float* __restrict__ outbuf, int N, int mode)
{
    int wave = threadIdx.x >> 6;
    int lane = threadIdx.x & 63;
    int n = blockIdx.x * 4 + wave;
    if (n >= N) return;

    const float2* wdp = (const float2*)Wdeg_t;
    float2 w0f = wdp[lane], w1f = wdp[64 + lane], w2f = wdp[128 + lane], w3f = wdp[192 + lane];
    f32x2 wd0 = {w0f.x, w0f.y}, wd1 = {w1f.x, w1f.y};
    f32x2 wd2 = {w2f.x, w2f.y}, wd3 = {w3f.x, w3f.y};

    int e0 = __builtin_amdgcn_readfirstlane(off[n]);
    int e1 = __builtin_amdgcn_readfirstlane(off[n + 1]);
    float2 qf = ((const float2*)qbuf)[(size_t)n * 64 + lane];
    const float QS = RSQRT_DH * INV_AVG;
    f32x2 qq = {qf.x * QS, qf.y * QS};
    f32x2 acc2 = {0.f, 0.f};
    float devacc = 0.0f;
    const float* edf = (const float*)edata;

    int ei = e0;
    if (mode == 0) {
        for (; ei + 7 < e1; ei += 8) {
            int sx[8];
            #pragma unroll
            for (int u = 0; u < 8; u++)
                sx[u] = __float_as_int(edf[(size_t)(2 * (ei + u)) * 4]);
            uint2 kv[8];
            #pragma unroll
            for (int u = 0; u < 8; u++)
                kv[u] = kv16[(size_t)sx[u] * 64 + lane];
            #pragma unroll
            for (int u = 0; u < 8; u++) {
                float4 h = edata[2 * (ei + u)], d = edata[2 * (ei + u) + 1];
                float al = h.z * edge_alpha(lane, qq, wd0, wd1, wd2, wd3, tab2, h.y, d, kv[u].x);
                f32x2 v = {al, al};
                acc2 = acc2 + v * up2(kv[u].y);
            }
        }
        for (; ei < e1; ei++) {
            float4 h = edata[2 * ei], d = edata[2 * ei + 1];
            int sA = __float_as_int(h.x);
            uint2 kv = kv16[(size_t)sA * 64 + lane];
            float al = h.z * edge_alpha(lane, qq, wd0, wd1, wd2, wd3, tab2, h.y, d, kv.x);
            f32x2 v = {al, al};
            acc2 = acc2 + v * up2(kv.y);
        }
        ((float2*)outbuf)[(size_t)n * 64 + lane] = make_float2(acc2.x, acc2.y);
    } else {
        int c = lane & 15;
        int g = lane >> 4;
        int ssel = ((c == 0) ? 0 : (c < 4) ? 16 : (c < 9) ? 32 : 48) + c;
        for (; ei + 7 < e1; ei += 8) {
            int sx[8];
            #pragma unroll
            for (int u = 0; u < 8; u++)
                sx[u] = __float_as_int(edf[(size_t)(2 * (ei + u)) * 4]);
            unsigned int kk[8];
            #pragma unroll
            for (int u = 0; u < 8; u++)
                kk[u] = k16p[(size_t)sx[u] * 64 + lane];
            #pragma unroll
            for (int u4 = 0; u4 < 2; u4++) {
                float al[4];
                #pragma unroll
                for (int v = 0; v < 4; v++) {
                    int u = u4 * 4 + v;
                    float4 h = edata[2 * (ei + u)], d = edata[2 * (ei + u) + 1];
                    al[v] = h.z * edge_alpha(lane, qq, wd0, wd1, wd2, wd3, tab2, h.y, d, kk[u]);
                }
                float ad0 = __shfl(al[0], ssel);
                float ad1 = __shfl(al[1], ssel);
                float ad2 = __shfl(al[2], ssel);
                float ad3 = __shfl(al[3], ssel);
                float ad = (g == 0) ? ad0 : (g == 1) ? ad1 : (g == 2) ? ad2 : ad3;
                devacc += ad * Yp[(size_t)(ei + u4 * 4 + g) * 16 + c];
            }
        }
        for (; ei < e1; ei++) {
            float4 h = edata[2 * ei], d = edata[2 * ei + 1];
            int sA = __float_as_int(h.x);
            unsigned int kA = k16p[(size_t)sA * 64 + lane];
            float al = h.z * edge_alpha(lane, qq, wd0, wd1, wd2, wd3, tab2, h.y, d, kA);
            float ad = __shfl(al, ssel);
            if (g == 0) devacc += ad * Yp[(size_t)ei * 16 + c];
        }
        devacc += __shfl_xor(devacc, 16, 64);
        devacc += __shfl_xor(devacc, 32, 64);
        if (lane < 16) outbuf[n * 16 + lane] = devacc;
    }
}

// ---------------------------------------------------------------------------
// Mega-fused exchange + next-t qkv (or readout). 512 threads, ct-half split.
// ---------------------------------------------------------------------------
__global__ __launch_bounds__(512) void exchange_fused_kernel(
    float* __restrict__ f, float* __restrict__ ev, const float* __restrict__ dEv,
    const unsigned int* __restrict__ B1, const float* __restrict__ Wex1,
    const float* __restrict__ bex1,
    const unsigned int* __restrict__ B2, const float* __restrict__ Wex2,
    const float* __restrict__ bex2,
    const unsigned int* __restrict__ Bq, const unsigned int* __restrict__ Bk,
    const unsigned int* __restrict__ Bv,
    float* __restrict__ qout, unsigned int* __restrict__ kvout,
    const float* __restrict__ bo1, const float* __restrict__ Wo2,
    const float* __restrict__ bo2, float* __restrict__ node_e,
    int last, int N)
{
    __shared__ unsigned int sA[64 * APITCH];  // f bf16 -> hid bf16 -> fnew bf16
    __shared__ float sev[64][17];
    __shared__ float sEvInv[64][4];
    __shared__ float sW1x[4][F];
    __shared__ float sW2x[F][4];
    __shared__ float sB1[F];
    __shared__ float sB2[F];
    __shared__ float sb2x[4];
    __shared__ float syb[64][4];
    __shared__ float sRB[F];
    __shared__ float sRW[F];
    __shared__ float spart[64][2];

    int tid = threadIdx.x;
    int n0 = blockIdx.x * 64;
    #pragma unroll
    for (int rep = 0; rep < 8; rep++) {
        int idx = rep * 512 + tid;
        int node = idx >> 6, jj = idx & 63;
        int n = n0 + node;
        float2 v = (n < N) ? ((const float2*)f)[(size_t)n * 64 + jj] : make_float2(0.f, 0.f);
        sA[node * APITCH + jj] = pk_bf2(v.x, v.y);
    }
    for (int idx = tid; idx < 64 * 16; idx += 512) {
        int node = idx >> 4, c = idx & 15;
        int n = n0 + node;
        sev[node][c] = (n < N) ? (ev[(size_t)n * 16 + c] + dEv[(size_t)n * 16 + c]) : 0.0f;
    }
    if (tid < 4 * F)
        sW1x[tid >> 7][tid & 127] = Wex1[(size_t)(128 + (tid >> 7)) * F + (tid & 127)];
    if (tid < F * 4)
        sW2x[tid >> 2][tid & 3] = Wex2[(size_t)(tid >> 2) * (F + 4) + 128 + (tid & 3)];
    if (tid < F) sB1[tid] = bex1[tid];
    else if (tid < 2 * F) sB2[tid - F] = bex2[tid - F];
    if (tid < 4) sb2x[tid] = bex2[F + tid];
    if (last) {
        if (tid < F) sRB[tid] = bo1[tid];
        else if (tid < 2 * F) sRW[tid - F] = Wo2[tid - F];
    }
    __syncthreads();
    if (tid < 256) {
        int node = tid >> 2, d = tid & 3;
        int c0 = (d == 0) ? 0 : (d == 1) ? 1 : (d == 2) ? 4 : 9;
        int c1 = (d == 0) ? 1 : (d == 1) ? 4 : (d == 2) ? 9 : 16;
        float a = 0.0f;
        for (int c = c0; c < c1; c++) { float v = sev[node][c]; a += v * v; }
        sEvInv[node][d] = a;
    }
    int wave = tid >> 6, lane = tid & 63;
    int rg = wave & 3, ch = wave >> 2;
    int quad = lane >> 4, col = lane & 15;
    int mrow = rg * 16 + col;
    s16x8 af[4];
    #pragma unroll
    for (int kb = 0; kb < 4; kb++) {
        FragU fu;
        fu.u = *(const uint4*)&sA[mrow * APITCH + kb * 16 + quad * 4];
        af[kb] = fu.s;
    }
    __syncthreads();
    float evq[4][4];
    #pragma unroll
    for (int r = 0; r < 4; r++) {
        int node = rg * 16 + quad * 4 + r;
        #pragma unroll
        for (int d = 0; d < 4; d++) evq[r][d] = sEvInv[node][d];
    }
    // GEMM1: hid = silu(f@Wex1[:128] + ev_inv@Wex1[128:] + b1) -> sA
    for (int c2 = 0; c2 < 4; c2++) {
        int ct = ch * 4 + c2;
        f32x4 acc = {0.f, 0.f, 0.f, 0.f};
        #pragma unroll
        for (int kb = 0; kb < 4; kb++) {
            FragU bu;
            bu.u = *(const uint4*)&B1[(size_t)((ct * 16 + kb * 4 + quad) * 16 + col) * 4];
            acc = __builtin_amdgcn_mfma_f32_16x16x32_bf16(af[kb], bu.s, acc, 0, 0, 0);
        }
        int j = ct * 16 + col;
        float w0 = sW1x[0][j], w1 = sW1x[1][j], w2 = sW1x[2][j], w3 = sW1x[3][j];
        float bj = sB1[j];
        #pragma unroll
        for (int r = 0; r < 4; r++) {
            float x = acc[r] + bj + evq[r][0] * w0 + evq[r][1] * w1
                    + evq[r][2] * w2 + evq[r][3] * w3;
            float h = silu_f(x);
            float other = __shfl_xor(h, 1, 64);
            if (!(lane & 1)) {
                int node = rg * 16 + quad * 4 + r;
                sA[node * APITCH + ct * 8 + (col >> 1)] = pk_bf2(h, other);
            }
        }
    }
    __syncthreads();
    s16x8 a2[4];
    #pragma unroll
    for (int kb = 0; kb < 4; kb++) {
        FragU fu;
        fu.u = *(const uint4*)&sA[mrow * APITCH + kb * 16 + quad * 4];
        a2[kb] = fu.s;
    }
    // yb2 (cols 128..131) per (node, d) thread — reads sA(hid)
    if (tid < 256) {
        int node = tid >> 2, d = tid & 3;
        float a = sb2x[d];
        for (int dw = 0; dw < 64; dw++) {
            unsigned int u = sA[node * APITCH + dw];
            a += up_lo(u) * sW2x[2 * dw][d] + up_hi(u) * sW2x[2 * dw + 1][d];
        }
        syb[node][d] = a;
    }
    __syncthreads();   // all sA(hid) reads done before overwrite with fnew
    // GEMM2: fnew = f + hid@Wex2[:, :128] + b2 -> write f + pack fnew -> sA
    for (int c2 = 0; c2 < 4; c2++) {
        int ct = ch * 4 + c2;
        f32x4 acc = {0.f, 0.f, 0.f, 0.f};
        #pragma unroll
        for (int kb = 0; kb < 4; kb++) {
            FragU bu;
            bu.u = *(const uint4*)&B2[(size_t)((ct * 16 + kb * 4 + quad) * 16 + col) * 4];
            acc = __builtin_amdgcn_mfma_f32_16x16x32_bf16(a2[kb], bu.s, acc, 0, 0, 0);
        }
        int j = ct * 16 + col;
        float bj = sB2[j];
        #pragma unroll
        for (int r = 0; r < 4; r++) {
            int node = rg * 16 + quad * 4 + r;
            int n = n0 + node;
            float fx = 0.0f;
            if (n < N) {
                size_t ix = (size_t)n * F + j;
                fx = f[ix] + acc[r] + bj;
                f[ix] = fx;
            }
            float other = __shfl_xor(fx, 1, 64);
            if (!(lane & 1)) sA[node * APITCH + ct * 8 + (col >> 1)] = pk_bf2(fx, other);
        }
    }
    __syncthreads();
    // ev update
    for (int idx = tid; idx < 64 * 16; idx += 512) {
        int node = idx >> 4, c = idx & 15;
        int n = n0 + node;
        if (n < N) ev[(size_t)n * 16 + c] = sev[node][c] * (1.0f + syb[node][deg_of(c)]);
    }
    s16x8 a3[4];
    #pragma unroll
    for (int kb = 0; kb < 4; kb++) {
        FragU fu;
        fu.u = *(const uint4*)&sA[mrow * APITCH + kb * 16 + quad * 4];
        a3[kb] = fu.s;
    }
    if (!last) {
        // q = fnew @ Wq[t+1] (fp32)
        for (int c2 = 0; c2 < 4; c2++) {
            int ct = ch * 4 + c2;
            f32x4 acc = {0.f, 0.f, 0.f, 0.f};
            #pragma unroll
            for (int kb = 0; kb < 4; kb++) {
                FragU bu;
                bu.u = *(const uint4*)&Bq[(size_t)((ct * 16 + kb * 4 + quad) * 16 + col) * 4];
                acc = __builtin_amdgcn_mfma_f32_16x16x32_bf16(a3[kb], bu.s, acc, 0, 0, 0);
            }
            #pragma unroll
            for (int r = 0; r < 4; r++) {
                int n = n0 + rg * 16 + quad * 4 + r;
                if (n < N) qout[(size_t)n * F + ct * 16 + col] = acc[r];
            }
        }
        // k and v = fnew @ Wk/Wv (bf16 packed, interleaved kv)
        for (int m = 0; m < 2; m++) {
            const unsigned int* B = (m == 0) ? Bk : Bv;
            for (int c2 = 0; c2 < 4; c2++) {
                int ct = ch * 4 + c2;
                f32x4 acc = {0.f, 0.f, 0.f, 0.f};
                #pragma unroll
                for (int kb = 0; kb < 4; kb++) {
                    FragU bu;
                    bu.u = *(const uint4*)&B[(size_t)((ct * 16 + kb * 4 + quad) * 16 + col) * 4];
                    acc = __builtin_amdgcn_mfma_f32_16x16x32_bf16(a3[kb], bu.s, acc, 0, 0, 0);
                }
                #pragma unroll
                for (int r = 0; r < 4; r++) {
                    float other = __shfl_xor(acc[r], 1, 64);
                    if (!(lane & 1)) {
                        int n = n0 + rg * 16 + quad * 4 + r;
                        if (n < N) {
                            size_t base = (size_t)n * 64 + ct * 8 + (col >> 1);
                            kvout[base * 2 + m] = pk_bf2(acc[r], other);
                        }
                    }
                }
            }
        }
    } else {
        // readout: node_e = silu(fnew@Wo1 + bo1) . Wo2 + bo2 (ct-half partials)
        float part[4] = {0.f, 0.f, 0.f, 0.f};
        for (int c2 = 0; c2 < 4; c2++) {
            int ct = ch * 4 + c2;
            f32x4 acc = {0.f, 0.f, 0.f, 0.f};
            #pragma unroll
            for (int kb = 0; kb < 4; kb++) {
                FragU bu;
                bu.u = *(const uint4*)&Bq[(size_t)((ct * 16 + kb * 4 + quad) * 16 + col) * 4];
                acc = __builtin_amdgcn_mfma_f32_16x16x32_bf16(a3[kb], bu.s, acc, 0, 0, 0);
            }
            int j = ct * 16 + col;
            float bj = sRB[j], wj = sRW[j];
            #pragma unroll
            for (int r = 0; r < 4; r++) part[r] += silu_f(acc[r] + bj) * wj;
        }
        #pragma unroll
        for (int r = 0; r < 4; r++) part[r] = red16_dpp(part[r]);
        if (col == 0) {
            #pragma unroll
            for (int r = 0; r < 4; r++) spart[rg * 16 + quad * 4 + r][ch] = part[r];
        }
        __syncthreads();
        if (tid < 64) {
            int n = n0 + tid;
            if (n < N) node_e[n] = spart[tid][0] + spart[tid][1] + bo2[0];
        }
    }
}

// ---------------------------------------------------------------------------
// energy[g] = sum_{batch[n]==g} node_e[n]
// ---------------------------------------------------------------------------
__global__ __launch_bounds__(256) void energy_reduce_kernel(
    const float* __restrict__ node_e, const int* __restrict__ batch,
    float* __restrict__ energy, int N)
{
    __shared__ float eacc[64];
    if (threadIdx.x < 64) eacc[threadIdx.x] = 0.0f;
    __syncthreads();
    for (int n = blockIdx.x * blockDim.x + threadIdx.x; n < N; n += gridDim.x * blockDim.x)
        atomicAdd(&eacc[batch[n]], node_e[n]);
    __syncthreads();
    if (threadIdx.x < 64) atomicAdd(&energy[threadIdx.x], eacc[threadIdx.x]);
}

// ---------------------------------------------------------------------------
extern "C" void kernel_launch(void* const* d_in, const int* in_sizes, int n_in,
                              void* d_out, int out_size, void* d_ws, size_t ws_size,
                              hipStream_t stream)
{
    const float* positions = (const float*)d_in[0];
    const int*   species   = (const int*)d_in[1];
    const int*   senders   = (const int*)d_in[2];
    const int*   receivers = (const int*)d_in[3];
    const int*   batch     = (const int*)d_in[4];
    const float* embed     = (const float*)d_in[5];
    const float* Wq    = (const float*)d_in[6];
    const float* Wk    = (const float*)d_in[7];
    const float* Wv    = (const float*)d_in[8];
    const float* Wo    = (const float*)d_in[9];
    const float* Wrbf1 = (const float*)d_in[10];
    const float* brbf1 = (const float*)d_in[11];
    const float* Wrbf2 = (const float*)d_in[12];
    const float* Wdeg  = (const float*)d_in[13];
    const float* Wq2   = (const float*)d_in[14];
    const float* Wk2   = (const float*)d_in[15];
    const float* Wex1  = (const float*)d_in[16];
    const float* bex1  = (const float*)d_in[17];
    const float* Wex2  = (const float*)d_in[18];
    const float* bex2  = (const float*)d_in[19];
    const float* Wo1   = (const float*)d_in[20];
    const float* bo1   = (const float*)d_in[21];
    const float* Wo2   = (const float*)d_in[22];
    const float* bo2   = (const float*)d_in[23];

    int N = in_sizes[0] / 3;
    int E = in_sizes[2];

    // ---- workspace layout (~115 MB) ----
    float* ws     = (float*)d_ws;
    float* Yp     = ws;  ws += (size_t)E * 16;        // CSR-ordered Y (30.7 MB)
    float4* edata = (float4*)ws; ws += (size_t)E * 8; // packed edge stream (15.4 MB)
    float* f      = ws;  ws += (size_t)N * F;
    float* evb    = ws;  ws += (size_t)N * 16;
    float* dEv    = ws;  ws += (size_t)N * 16;
    float* q      = ws;  ws += (size_t)N * F;         // doubles as agg
    float* node_e = ws;  ws += (size_t)N;
    float* Cb     = ws;  ws += (size_t)E;             // C only (for ev0)
    uint2* tab2 = (uint2*)ws;  ws += (size_t)TINTER * TAB_N * 64 * 2;
    uint2* kv16 = (uint2*)ws;  ws += (size_t)N * 64 * 2;
    unsigned int* k16p = (unsigned int*)ws;  ws += (size_t)N * 64;
    int* sp    = (int*)ws;  ws += E;
    int* rcvp  = (int*)ws;  ws += E;
    int* cnt   = (int*)ws;  ws += N;
    int* off   = (int*)ws;  ws += N + 1;
    int* cur   = (int*)ws;  ws += N;
    int* elist = (int*)ws;  ws += E;
    int* bsum  = (int*)ws;  ws += 1024;
    int* boff  = (int*)ws;  ws += 1024;
    unsigned int* Wpk  = (unsigned int*)ws;  ws += 18 * 8192;
    unsigned int* Wpk2 = (unsigned int*)ws;  ws += 7 * 8192;

    // ---- CSR build (parallel scan) ----
    int nb = (N + SCB - 1) / SCB;
    hipMemsetAsync(cnt, 0, (size_t)N * sizeof(int), stream);
    count_kernel<<<(E + 255) / 256, 256, 0, stream>>>(receivers, cnt, E);
    scan_part_kernel<<<nb, SCB, 0, stream>>>(cnt, off, bsum, N);
    scan_mid_kernel<<<1, 1024, 0, stream>>>(bsum, boff, off, N, nb);
    scan_add_kernel<<<(N + 255) / 256, 256, 0, stream>>>(off, cur, boff, N);
    scatter_kernel<<<(E + 255) / 256, 256, 0, stream>>>(receivers, cur, elist, E);

    // ---- geometry + packing + table ----
    edge_geom_csr_kernel<<<(E + 255) / 256, 256, 0, stream>>>(elist, positions, senders,
                                                              receivers, sp, rcvp, Cb,
                                                              edata, Yp, E);
    pack_w_kernel<<<(18 * 8192 + 255) / 256, 256, 0, stream>>>(Wq, Wk, Wv, Wo, Wq2, Wk2, Wpk);
    pack_ex_kernel<<<(7 * 8192 + 255) / 256, 256, 0, stream>>>(Wex1, Wex2, Wo1, Wpk2);
    build_table_kernel<<<dim3(TAB_N / 4, TINTER), 256, 0, stream>>>(Wrbf1, brbf1, Wrbf2,
                                                                    (unsigned int*)tab2);
    ev0_kernel<<<(N + 15) / 16, 256, 0, stream>>>(off, Yp, Cb, evb, N);
    embed_kernel<<<N, F, 0, stream>>>(species, embed, f, N);

    int nmb = (N + 63) / 64;
    int npb = (N + 3) / 4;
    int edb = (E + 255) / 256;
    // t=0 qkv
    node_gemm_mfma_kernel<<<nmb, 512, 0, stream>>>(f, Wpk + 0 * 8192, Wpk + 3 * 8192,
                                                   Wpk + 6 * 8192, q, (unsigned int*)kv16, N);
    for (int t = 0; t < TINTER; t++) {
        const unsigned int* Wpk_o  = Wpk + (size_t)(3 * 3 + t) * 8192;
        const unsigned int* Wpk_q2 = Wpk + (size_t)(4 * 3 + t) * 8192;
        const unsigned int* Wpk_k2 = Wpk + (size_t)(5 * 3 + t) * 8192;
        const uint2* tab_t = tab2 + (size_t)t * TAB_N * 64;
        const float* Wdeg_t = Wdeg + (size_t)t * 4 * F;
        int last = (t == TINTER - 1);
        const unsigned int* Bq_n = last ? (Wpk2 + (size_t)6 * 8192)
                                        : (Wpk + (size_t)(0 * 3 + t + 1) * 8192);
        const unsigned int* Bk_n = Wpk + (size_t)(1 * 3 + (last ? t : t + 1)) * 8192;
        const unsigned int* Bv_n = Wpk + (size_t)(2 * 3 + (last ? t : t + 1)) * 8192;

        dd_kernel<<<edb, 256, 0, stream>>>(sp, rcvp, evb, edata, E);
        edge_pass_node_kernel<<<npb, 256, 0, stream>>>(off, edata, Yp,
            q, kv16, nullptr, tab_t, Wdeg_t, q /*agg: aliases qbuf, own-row only*/, N, 0);
        fused_o_qk_kernel<<<nmb, 512, 0, stream>>>(q, Wpk_o, Wpk_q2, Wpk_k2,
                                                   f, q, k16p, N);
        edge_pass_node_kernel<<<npb, 256, 0, stream>>>(off, edata, Yp,
            q, nullptr, k16p, tab_t, Wdeg_t, dEv, N, 1);
        exchange_fused_kernel<<<nmb, 512, 0, stream>>>(f, evb, dEv,
            Wpk2 + (size_t)t * 8192, Wex1 + (size_t)t * (F + 4) * F, bex1 + (size_t)t * F,
            Wpk2 + (size_t)(3 + t) * 8192, Wex2 + (size_t)t * F * (F + 4),
            bex2 + (size_t)t * (F + 4),
            Bq_n, Bk_n, Bv_n, q, (unsigned int*)kv16,
            bo1, Wo2, bo2, node_e, last, N);
    }
    hipMemsetAsync(d_out, 0, (size_t)out_size * sizeof(float), stream);
    energy_reduce_kernel<<<16, 256, 0, stream>>>(node_e, batch, (float*)d_out, N);
}

// Round 17
// 688.892 us; speedup vs baseline: 1.0599x; 1.0599x over previous
//
#include <hip/hip_runtime.h>
#include <math.h>

// ---- static config (matches reference) ----
#define F 128
#define KRBF 32
#define TINTER 3
#define RMAX 5.0f
#define INV_AVG (1.0f/16.0f)
#define GAMMA 40.96f               // (KRBF/RMAX)^2
#define RSQRT_DH 0.17677669529663689f  // 1/sqrt(32)
#define PI_F 3.14159265358979323846f
#define TAB_N 2048                 // w(r) interpolation table entries over [0, RMAX]
#define APITCH 68                  // LDS A-tile pitch in dwords (16B-aligned rows)
#define SCB 256                    // scan block size

__device__ __forceinline__ float silu_f(float x) { return x / (1.0f + expf(-x)); }
__device__ __forceinline__ int deg_of(int c) { return (c == 0) ? 0 : (c < 4) ? 1 : (c < 9) ? 2 : 3; }

// bf16x2 pack/unpack: packed word = (elem0) | (elem1 << 16), RNE rounding
__device__ __forceinline__ unsigned int pk_bf2(float lo, float hi) {
    unsigned int a = __float_as_uint(lo), b = __float_as_uint(hi);
    unsigned int ar = (a + 0x7fffu + ((a >> 16) & 1u)) >> 16;
    unsigned int br = (b + 0x7fffu + ((b >> 16) & 1u)) >> 16;
    return ar | (br << 16);
}
__device__ __forceinline__ float up_lo(unsigned int u) { return __uint_as_float(u << 16); }
__device__ __forceinline__ float up_hi(unsigned int u) { return __uint_as_float(u & 0xffff0000u); }

typedef short s16x8 __attribute__((ext_vector_type(8)));
typedef float f32x4 __attribute__((ext_vector_type(4)));
typedef float f32x2 __attribute__((ext_vector_type(2)));
union FragU { uint4 u; s16x8 s; };

__device__ __forceinline__ f32x2 up2(unsigned int u) {
    f32x2 r; r.x = up_lo(u); r.y = up_hi(u); return r;
}

// 16-lane (head-group) sum via DPP — pure VALU, no LDS-pipe bpermute.
__device__ __forceinline__ float red16_dpp(float p) {
    p += __uint_as_float((unsigned)__builtin_amdgcn_update_dpp(
        0, (int)__float_as_uint(p), 0xB1, 0xF, 0xF, true));   // quad_perm [1,0,3,2]
    p += __uint_as_float((unsigned)__builtin_amdgcn_update_dpp(
        0, (int)__float_as_uint(p), 0x4E, 0xF, 0xF, true));   // quad_perm [2,3,0,1]
    p += __uint_as_float((unsigned)__builtin_amdgcn_update_dpp(
        0, (int)__float_as_uint(p), 0x124, 0xF, 0xF, true));  // row_ror:4
    p += __uint_as_float((unsigned)__builtin_amdgcn_update_dpp(
        0, (int)__float_as_uint(p), 0x128, 0xF, 0xF, true));  // row_ror:8
    return p;
}

// ---------------------------------------------------------------------------
// CSR build: count -> parallel 3-phase scan -> scatter
// ---------------------------------------------------------------------------
__global__ void count_kernel(const int* __restrict__ rcv, int* __restrict__ cnt, int E)
{
    int e = blockIdx.x * blockDim.x + threadIdx.x;
    if (e < E) atomicAdd(&cnt[rcv[e]], 1);
}

__global__ __launch_bounds__(SCB) void scan_part_kernel(const int* __restrict__ cnt,
                                                        int* __restrict__ off,
                                                        int* __restrict__ bsum, int N)
{
    __shared__ int s[SCB];
    int tid = threadIdx.x;
    int i = blockIdx.x * SCB + tid;
    int v = (i < N) ? cnt[i] : 0;
    s[tid] = v;
    __syncthreads();
    for (int st = 1; st < SCB; st <<= 1) {
        int t = (tid >= st) ? s[tid - st] : 0;
        __syncthreads();
        s[tid] += t;
        __syncthreads();
    }
    if (i < N) off[i] = s[tid] - v;
    if (tid == SCB - 1) bsum[blockIdx.x] = s[tid];
}

__global__ __launch_bounds__(1024) void scan_mid_kernel(const int* __restrict__ bsum,
                                                        int* __restrict__ boff,
                                                        int* __restrict__ off, int N, int nb)
{
    __shared__ int s[1024];
    int tid = threadIdx.x;
    int v = (tid < nb) ? bsum[tid] : 0;
    s[tid] = v;
    __syncthreads();
    for (int st = 1; st < 1024; st <<= 1) {
        int t = (tid >= st) ? s[tid - st] : 0;
        __syncthreads();
        s[tid] += t;
        __syncthreads();
    }
    if (tid < nb) boff[tid] = s[tid] - v;
    if (tid == 1023) off[N] = s[1023];
}

__global__ void scan_add_kernel(int* __restrict__ off, int* __restrict__ cur,
                                const int* __restrict__ boff, int N)
{
    int i = blockIdx.x * blockDim.x + threadIdx.x;
    if (i < N) {
        int v = off[i] + boff[i / SCB];
        off[i] = v; cur[i] = v;
    }
}

__global__ void scatter_kernel(const int* __restrict__ rcv, int* __restrict__ cur,
                               int* __restrict__ elist, int E)
{
    int e = blockIdx.x * blockDim.x + threadIdx.x;
    if (e < E) {
        int p = atomicAdd(&cur[rcv[e]], 1);
        elist[p] = e;
    }
}

// ---------------------------------------------------------------------------
// Fused edge geometry in CSR order. edata[ei] = {s, r, C, pad | dd0..3}
// ---------------------------------------------------------------------------
__global__ void edge_geom_csr_kernel(const int* __restrict__ elist,
                                     const float* __restrict__ pos,
                                     const int* __restrict__ snd,
                                     const int* __restrict__ rcv,
                                     int* __restrict__ sp, int* __restrict__ rcvp,
                                     float* __restrict__ Cb,
                                     float4* __restrict__ edata,
                                     float* __restrict__ Yp, int E)
{
    int ei = blockIdx.x * blockDim.x + threadIdx.x;
    if (ei >= E) return;
    int e = elist[ei];
    int s = snd[e], rc = rcv[e];
    sp[ei] = s; rcvp[ei] = rc;
    float vx = pos[rc * 3 + 0] - pos[s * 3 + 0];
    float vy = pos[rc * 3 + 1] - pos[s * 3 + 1];
    float vz = pos[rc * 3 + 2] - pos[s * 3 + 2];
    float r = sqrtf(vx * vx + vy * vy + vz * vz);
    float rinv = 1.0f / fmaxf(r, 1e-9f);
    float x = vx * rinv, y = vy * rinv, z = vz * rinv;
    float x2 = x * x, y2 = y * y, z2 = z * z;
    const float s3 = 1.7320508075688772f, s5 = 2.23606797749979f, s15 = 3.872983346207417f;
    const float s70 = 8.366600265340756f, s105 = 10.246950765959598f;
    const float s42 = 6.48074069840786f, s7 = 2.6457513110645907f;
    float Y[16];
    Y[0] = 1.0f;
    Y[1] = s3 * x; Y[2] = s3 * y; Y[3] = s3 * z;
    Y[4] = s15 * x * y; Y[5] = s15 * y * z; Y[6] = 0.5f * s5 * (3.0f * z2 - 1.0f);
    Y[7] = s15 * x * z; Y[8] = 0.5f * s15 * (x2 - y2);
    Y[9]  = 0.25f * s70 * y * (3.0f * x2 - y2);
    Y[10] = s105 * x * y * z;
    Y[11] = 0.25f * s42 * y * (5.0f * z2 - 1.0f);
    Y[12] = 0.5f * s7 * z * (5.0f * z2 - 3.0f);
    Y[13] = 0.25f * s42 * x * (5.0f * z2 - 1.0f);
    Y[14] = 0.5f * s105 * z * (x2 - y2);
    Y[15] = 0.25f * s70 * x * (x2 - 3.0f * y2);
    float C = (r < RMAX) ? 0.5f * (cosf(PI_F * r / RMAX) + 1.0f) : 0.0f;
    Cb[ei] = C;
    edata[2 * ei] = make_float4(__int_as_float(s), r, C, 0.0f);
    #pragma unroll
    for (int c = 0; c < 16; c++) Yp[(size_t)ei * 16 + c] = Y[c];
}

// ---------------------------------------------------------------------------
// ev0[n] = sum_{ei in CSR(n)} Yp[ei]*C[ei] * INV_AVG
// ---------------------------------------------------------------------------
__global__ void ev0_kernel(const int* __restrict__ off,
                           const float* __restrict__ Yp, const float* __restrict__ Cb,
                           float* __restrict__ ev, int N)
{
    int n = blockIdx.x * 16 + (threadIdx.x >> 4);
    int c = threadIdx.x & 15;
    if (n >= N) return;
    float acc = 0.0f;
    int e0 = off[n], e1 = off[n + 1];
    for (int ei = e0; ei < e1; ei++)
        acc += Yp[(size_t)ei * 16 + c] * Cb[ei];
    ev[n * 16 + c] = acc * INV_AVG;
}

// ---------------------------------------------------------------------------
// f = embed[species]
// ---------------------------------------------------------------------------
__global__ void embed_kernel(const int* __restrict__ species,
                             const float* __restrict__ embed,
                             float* __restrict__ f, int N)
{
    int n = blockIdx.x;
    if (n >= N) return;
    int j = threadIdx.x;
    f[n * F + j] = embed[species[n] * F + j];
}

// ---------------------------------------------------------------------------
// Pack 18 128x128 fp32 weight matrices into MFMA B-operand bf16 layout.
// ---------------------------------------------------------------------------
__global__ void pack_w_kernel(const float* __restrict__ Wq, const float* __restrict__ Wk,
                              const float* __restrict__ Wv, const float* __restrict__ Wo,
                              const float* __restrict__ Wq2, const float* __restrict__ Wk2,
                              unsigned int* __restrict__ Wpk)
{
    int tid = blockIdx.x * blockDim.x + threadIdx.x;
    if (tid >= 18 * 8192) return;
    int mat = tid >> 13;
    int rem = tid & 8191;
    int iw = rem & 3;
    int n = (rem >> 2) & 15;
    int quad = (rem >> 6) & 3;
    int kb = (rem >> 8) & 3;
    int ct = rem >> 10;
    const float* fam = (mat < 3) ? Wq : (mat < 6) ? Wk : (mat < 9) ? Wv
                     : (mat < 12) ? Wo : (mat < 15) ? Wq2 : Wk2;
    const float* src = fam + (size_t)(mat % 3) * F * F;
    int k = kb * 32 + quad * 8 + iw * 2;
    int col = ct * 16 + n;
    Wpk[tid] = pk_bf2(src[k * F + col], src[(k + 1) * F + col]);
}

// Pack the 7 exchange/readout 128x128 submatrices in one dispatch
__global__ void pack_ex_kernel(const float* __restrict__ Wex1, const float* __restrict__ Wex2,
                               const float* __restrict__ Wo1, unsigned int* __restrict__ Wpk2)
{
    int tid = blockIdx.x * blockDim.x + threadIdx.x;
    if (tid >= 7 * 8192) return;
    int mat = tid >> 13;
    int rem = tid & 8191;
    int iw = rem & 3;
    int n = (rem >> 2) & 15;
    int quad = (rem >> 6) & 3;
    int kb = (rem >> 8) & 3;
    int ct = rem >> 10;
    const float* src; int stride;
    if (mat < 3)      { src = Wex1 + (size_t)mat * (F + 4) * F; stride = F; }
    else if (mat < 6) { src = Wex2 + (size_t)(mat - 3) * F * (F + 4); stride = F + 4; }
    else              { src = Wo1; stride = F; }
    int k = kb * 32 + quad * 8 + iw * 2;
    int col = ct * 16 + n;
    Wpk2[tid] = pk_bf2(src[(size_t)k * stride + col], src[(size_t)(k + 1) * stride + col]);
}

// ---------------------------------------------------------------------------
// Build paired bf16 w(r) table directly (entry i holds w_i and w_{i+1})
// ---------------------------------------------------------------------------
__global__ __launch_bounds__(256) void build_table_kernel(
    const float* __restrict__ Wrbf1_all, const float* __restrict__ brbf1_all,
    const float* __restrict__ Wrbf2_all, unsigned int* __restrict__ tab2w)
{
    int wave = threadIdx.x >> 6;
    int lane = threadIdx.x & 63;
    int idx = blockIdx.x * 4 + wave;
    int t = blockIdx.y;
    const float* W1 = Wrbf1_all + (size_t)t * KRBF * F;
    const float* b1 = brbf1_all + (size_t)t * F;
    const float* W2 = Wrbf2_all + (size_t)t * F * F;
    float r = idx * (RMAX / (TAB_N - 1));
    __shared__ float sR[4][KRBF];
    __shared__ float sH[4][F];
    if (lane < KRBF) {
        float mu = lane * (RMAX / (KRBF - 1));
        float d = r - mu;
        sR[wave][lane] = expf(-GAMMA * d * d);
    }
    __syncthreads();
    float h0 = b1[lane], h1 = b1[lane + 64];
    #pragma unroll
    for (int kk = 0; kk < KRBF; kk++) {
        float rv = sR[wave][kk];
        h0 += rv * W1[kk * F + lane];
        h1 += rv * W1[kk * F + lane + 64];
    }
    sH[wave][lane] = silu_f(h0);
    sH[wave][lane + 64] = silu_f(h1);
    __syncthreads();
    float w0 = 0.0f, w1 = 0.0f;
    for (int i = 0; i < F; i++) {
        float hv = sH[wave][i];
        w0 += hv * W2[i * F + 2 * lane];
        w1 += hv * W2[i * F + 2 * lane + 1];
    }
    unsigned int w = pk_bf2(w0, w1);
    size_t base = ((size_t)t * TAB_N + idx) * 64 + lane;   // uint2 index
    tab2w[base * 2] = w;
    if (idx > 0) tab2w[(base - 64) * 2 + 1] = w;
    if (idx == TAB_N - 1) tab2w[base * 2 + 1] = w;
}

// ---------------------------------------------------------------------------
// edata[ei].dd = deg_reduce(ev[sp[ei]] * ev[rcvp[ei]])  (second 16B half)
// ---------------------------------------------------------------------------
__global__ void dd_kernel(const int* __restrict__ sp, const int* __restrict__ rcvp,
                          const float* __restrict__ ev, float4* __restrict__ edata, int E)
{
    int ei = blockIdx.x * blockDim.x + threadIdx.x;
    if (ei >= E) return;
    int s = sp[ei], rc = rcvp[ei];
    const float4* a = (const float4*)(ev + (size_t)s * 16);
    const float4* b = (const float4*)(ev + (size_t)rc * 16);
    float4 a0 = a[0], a1 = a[1], a2 = a[2], a3 = a[3];
    float4 b0 = b[0], b1 = b[1], b2 = b[2], b3 = b[3];
    float d0 = a0.x * b0.x;
    float d1 = a0.y * b0.y + a0.z * b0.z + a0.w * b0.w;
    float d2 = a1.x * b1.x + a1.y * b1.y + a1.z * b1.z + a1.w * b1.w + a2.x * b2.x;
    float d3 = a2.y * b2.y + a2.z * b2.z + a2.w * b2.w
             + a3.x * b3.x + a3.y * b3.y + a3.z * b3.z + a3.w * b3.w;
    edata[2 * ei + 1] = make_float4(d0, d1, d2, d3);
}

// ---------------------------------------------------------------------------
// MFMA node GEMM (t=0 qkv): 512 threads, 8 waves = (row-group, ct-half).
// ---------------------------------------------------------------------------
__global__ __launch_bounds__(512) void node_gemm_mfma_kernel(
    const float* __restrict__ A,
    const unsigned int* __restrict__ B0, const unsigned int* __restrict__ B1,
    const unsigned int* __restrict__ B2,
    float* __restrict__ out0, unsigned int* __restrict__ out1,
    int N)
{
    __shared__ unsigned int sA[64 * APITCH];
    int tid = threadIdx.x;
    int n0 = blockIdx.x * 64;
    #pragma unroll
    for (int rep = 0; rep < 8; rep++) {
        int idx = rep * 512 + tid;
        int node = idx >> 6, jj = idx & 63;
        int n = n0 + node;
        float2 v = (n < N) ? ((const float2*)A)[(size_t)n * 64 + jj] : make_float2(0.f, 0.f);
        sA[node * APITCH + jj] = pk_bf2(v.x, v.y);
    }
    __syncthreads();
    int wave = tid >> 6, lane = tid & 63;
    int rg = wave & 3, ch = wave >> 2;
    int quad = lane >> 4, col = lane & 15;
    int mrow = rg * 16 + col;
    s16x8 af[4];
    #pragma unroll
    for (int kb = 0; kb < 4; kb++) {
        FragU fu;
        fu.u = *(const uint4*)&sA[mrow * APITCH + kb * 16 + quad * 4];
        af[kb] = fu.s;
    }
    for (int m = 0; m < 3; m++) {
        const unsigned int* B = (m == 0) ? B0 : (m == 1) ? B1 : B2;
        for (int c2 = 0; c2 < 4; c2++) {
            int ct = ch * 4 + c2;
            f32x4 acc = {0.f, 0.f, 0.f, 0.f};
            #pragma unroll
            for (int kb = 0; kb < 4; kb++) {
                FragU bu;
                bu.u = *(const uint4*)&B[(size_t)((ct * 16 + kb * 4 + quad) * 16 + col) * 4];
                acc = __builtin_amdgcn_mfma_f32_16x16x32_bf16(af[kb], bu.s, acc, 0, 0, 0);
            }
            if (m == 0) {
                #pragma unroll
                for (int r = 0; r < 4; r++) {
                    int n = n0 + rg * 16 + quad * 4 + r;
                    if (n < N) out0[(size_t)n * F + ct * 16 + col] = acc[r];
                }
            } else {
                #pragma unroll
                for (int r = 0; r < 4; r++) {
                    float other = __shfl_xor(acc[r], 1, 64);
                    if (!(lane & 1)) {
                        int n = n0 + rg * 16 + quad * 4 + r;
                        if (n < N) {
                            size_t base = (size_t)n * 64 + ct * 8 + (col >> 1);
                            out1[base * 2 + (m - 1)] = pk_bf2(acc[r], other);
                        }
                    }
                }
            }
        }
    }
}

// ---------------------------------------------------------------------------
// Fused: f += agg@Wo ; q = f@Wq2 (fp32); k2 = f@Wk2 (bf16). 512 thr, ct-split.
// agg may alias qout (input fully staged before any write).
// ---------------------------------------------------------------------------
__global__ __launch_bounds__(512) void fused_o_qk_kernel(
    const float* __restrict__ agg,
    const unsigned int* __restrict__ Bo, const unsigned int* __restrict__ Bq2,
    const unsigned int* __restrict__ Bk2,
    float* __restrict__ f, float* __restrict__ qout, unsigned int* __restrict__ k16p,
    int N)
{
    __shared__ unsigned int sA[64 * APITCH];
    int tid = threadIdx.x;
    int n0 = blockIdx.x * 64;
    #pragma unroll
    for (int rep = 0; rep < 8; rep++) {
        int idx = rep * 512 + tid;
        int node = idx >> 6, jj = idx & 63;
        int n = n0 + node;
        float2 v = (n < N) ? ((const float2*)agg)[(size_t)n * 64 + jj] : make_float2(0.f, 0.f);
        sA[node * APITCH + jj] = pk_bf2(v.x, v.y);
    }
    __syncthreads();
    int wave = tid >> 6, lane = tid & 63;
    int rg = wave & 3, ch = wave >> 2;
    int quad = lane >> 4, col = lane & 15;
    int mrow = rg * 16 + col;
    s16x8 af[4];
    #pragma unroll
    for (int kb = 0; kb < 4; kb++) {
        FragU fu;
        fu.u = *(const uint4*)&sA[mrow * APITCH + kb * 16 + quad * 4];
        af[kb] = fu.s;
    }
    __syncthreads();
    // GEMM1: f_new = f + agg@Wo -> write f (fp32) + pack f_new into sA (bf16)
    for (int c2 = 0; c2 < 4; c2++) {
        int ct = ch * 4 + c2;
        f32x4 acc = {0.f, 0.f, 0.f, 0.f};
        #pragma unroll
        for (int kb = 0; kb < 4; kb++) {
            FragU bu;
            bu.u = *(const uint4*)&Bo[(size_t)((ct * 16 + kb * 4 + quad) * 16 + col) * 4];
            acc = __builtin_amdgcn_mfma_f32_16x16x32_bf16(af[kb], bu.s, acc, 0, 0, 0);
        }
        #pragma unroll
        for (int r = 0; r < 4; r++) {
            int node = rg * 16 + quad * 4 + r;
            int n = n0 + node;
            float fx = 0.0f;
            if (n < N) {
                size_t ix = (size_t)n * F + ct * 16 + col;
                fx = f[ix] + acc[r];
                f[ix] = fx;
            }
            float other = __shfl_xor(fx, 1, 64);
            if (!(lane & 1)) sA[node * APITCH + ct * 8 + (col >> 1)] = pk_bf2(fx, other);
        }
    }
    __syncthreads();
    s16x8 a2[4];
    #pragma unroll
    for (int kb = 0; kb < 4; kb++) {
        FragU fu;
        fu.u = *(const uint4*)&sA[mrow * APITCH + kb * 16 + quad * 4];
        a2[kb] = fu.s;
    }
    // GEMM2a: q = f_new @ Wq2 (fp32)
    for (int c2 = 0; c2 < 4; c2++) {
        int ct = ch * 4 + c2;
        f32x4 acc = {0.f, 0.f, 0.f, 0.f};
        #pragma unroll
        for (int kb = 0; kb < 4; kb++) {
            FragU bu;
            bu.u = *(const uint4*)&Bq2[(size_t)((ct * 16 + kb * 4 + quad) * 16 + col) * 4];
            acc = __builtin_amdgcn_mfma_f32_16x16x32_bf16(a2[kb], bu.s, acc, 0, 0, 0);
        }
        #pragma unroll
        for (int r = 0; r < 4; r++) {
            int n = n0 + rg * 16 + quad * 4 + r;
            if (n < N) qout[(size_t)n * F + ct * 16 + col] = acc[r];
        }
    }
    // GEMM2b: k2 = f_new @ Wk2 (bf16 packed)
    for (int c2 = 0; c2 < 4; c2++) {
        int ct = ch * 4 + c2;
        f32x4 acc = {0.f, 0.f, 0.f, 0.f};
        #pragma unroll
        for (int kb = 0; kb < 4; kb++) {
            FragU bu;
            bu.u = *(const uint4*)&Bk2[(size_t)((ct * 16 + kb * 4 + quad) * 16 + col) * 4];
            acc = __builtin_amdgcn_mfma_f32_16x16x32_bf16(a2[kb], bu.s, acc, 0, 0, 0);
        }
        #pragma unroll
        for (int r = 0; r < 4; r++) {
            float other = __shfl_xor(acc[r], 1, 64);
            if (!(lane & 1)) {
                int n = n0 + rg * 16 + quad * 4 + r;
                if (n < N) k16p[(size_t)n * 64 + ct * 8 + (col >> 1)] = pk_bf2(acc[r], other);
            }
        }
    }
}

// ---------------------------------------------------------------------------
// Per-edge alpha (q pre-scaled). Table row base scalarized; DPP reduce.
// ---------------------------------------------------------------------------
__device__ __forceinline__ float edge_alpha(
    int lane, f32x2 qq, f32x2 wd0, f32x2 wd1, f32x2 wd2, f32x2 wd3,
    const uint2* __restrict__ tab2, float rr, float4 dd, unsigned int ku)
{
    float u = rr * ((float)(TAB_N - 1) / RMAX);
    int i0 = (int)u;
    i0 = (i0 > TAB_N - 2) ? (TAB_N - 2) : i0;
    float fr = u - (float)i0;
    int i0s = __builtin_amdgcn_readfirstlane(i0);
    uint2 tp = (tab2 + (size_t)i0s * 64)[lane];
    f32x2 a = up2(tp.x), b = up2(tp.y);
    f32x2 fr2 = {fr, fr};
    f32x2 w = a + fr2 * (b - a);
    f32x2 d0 = {dd.x, dd.x}, d1 = {dd.y, dd.y}, d2 = {dd.z, dd.z}, d3 = {dd.w, dd.w};
    w = w + d0 * wd0 + d1 * wd1 + d2 * wd2 + d3 * wd3;
    f32x2 p2 = qq * w * up2(ku);
    return red16_dpp(p2.x + p2.y);
}

// ---------------------------------------------------------------------------
// Node-centric fused edge pass; packed scalar edge stream (edata).
// Known-best r15 configuration: 4-way unroll, 32 VGPR, ~62% occupancy.
// ---------------------------------------------------------------------------
__global__ __launch_bounds__(256) void edge_pass_node_kernel(
    const int* __restrict__ off, const float4* __restrict__ edata,
    const float* __restrict__ Yp,
    const float* __restrict__ qbuf,
    const uint2* __restrict__ kv16, const unsigned int* __restrict__ k16p,
    const uint2* __restrict__ tab2, const float* __restrict__ Wdeg_t,
    float* __restrict__ outbuf, int N, int mode)
{
    int wave = threadIdx.x >> 6;
    int lane = threadIdx.x & 63;
    int n = blockIdx.x * 4 + wave;
    if (n >= N) return;

    const float2* wdp = (const float2*)Wdeg_t;
    float2 w0f = wdp[lane], w1f = wdp[64 + lane], w2f = wdp[128 + lane], w3f = wdp[192 + lane];
    f32x2 wd0 = {w0f.x, w0f.y}, wd1 = {w1f.x, w1f.y};
    f32x2 wd2 = {w2f.x, w2f.y}, wd3 = {w3f.x, w3f.y};

    int e0 = __builtin_amdgcn_readfirstlane(off[n]);
    int e1 = __builtin_amdgcn_readfirstlane(off[n + 1]);
    float2 qf = ((const float2*)qbuf)[(size_t)n * 64 + lane];
    const float QS = RSQRT_DH * INV_AVG;
    f32x2 qq = {qf.x * QS, qf.y * QS};
    f32x2 acc2 = {0.f, 0.f};
    float devacc = 0.0f;

    int ei = e0;
    if (mode == 0) {
        for (; ei + 3 < e1; ei += 4) {
            float4 hA = edata[2 * ei],     dA = edata[2 * ei + 1];
            float4 hB = edata[2 * ei + 2], dB = edata[2 * ei + 3];
            float4 hC = edata[2 * ei + 4], dC = edata[2 * ei + 5];
            float4 hD = edata[2 * ei + 6], dD = edata[2 * ei + 7];
            int sA = __float_as_int(hA.x), sB = __float_as_int(hB.x);
            int sC = __float_as_int(hC.x), sD = __float_as_int(hD.x);
            uint2 kvA = kv16[(size_t)sA * 64 + lane];
            uint2 kvB = kv16[(size_t)sB * 64 + lane];
            uint2 kvC = kv16[(size_t)sC * 64 + lane];
            uint2 kvD = kv16[(size_t)sD * 64 + lane];
            float alA = hA.z * edge_alpha(lane, qq, wd0, wd1, wd2, wd3, tab2, hA.y, dA, kvA.x);
            float alB = hB.z * edge_alpha(lane, qq, wd0, wd1, wd2, wd3, tab2, hB.y, dB, kvB.x);
            float alC = hC.z * edge_alpha(lane, qq, wd0, wd1, wd2, wd3, tab2, hC.y, dC, kvC.x);
            float alD = hD.z * edge_alpha(lane, qq, wd0, wd1, wd2, wd3, tab2, hD.y, dD, kvD.x);
            f32x2 vA = {alA, alA}, vB = {alB, alB}, vC = {alC, alC}, vD = {alD, alD};
            acc2 = acc2 + vA * up2(kvA.y) + vB * up2(kvB.y)
                        + vC * up2(kvC.y) + vD * up2(kvD.y);
        }
        for (; ei < e1; ei++) {
            float4 hA = edata[2 * ei], dA = edata[2 * ei + 1];
            int sA = __float_as_int(hA.x);
            uint2 kvA = kv16[(size_t)sA * 64 + lane];
            float alA = hA.z * edge_alpha(lane, qq, wd0, wd1, wd2, wd3, tab2, hA.y, dA, kvA.x);
            f32x2 vA = {alA, alA};
            acc2 = acc2 + vA * up2(kvA.y);
        }
        ((float2*)outbuf)[(size_t)n * 64 + lane] = make_float2(acc2.x, acc2.y);
    } else {
        int c = lane & 15;
        int g = lane >> 4;
        int ssel = ((c == 0) ? 0 : (c < 4) ? 16 : (c < 9) ? 32 : 48) + c;
        for (; ei + 3 < e1; ei += 4) {
            float4 hA = edata[2 * ei],     dA = edata[2 * ei + 1];
            float4 hB = edata[2 * ei + 2], dB = edata[2 * ei + 3];
            float4 hC = edata[2 * ei + 4], dC = edata[2 * ei + 5];
            float4 hD = edata[2 * ei + 6], dD = edata[2 * ei + 7];
            int sA = __float_as_int(hA.x), sB = __float_as_int(hB.x);
            int sC = __float_as_int(hC.x), sD = __float_as_int(hD.x);
            unsigned int kA = k16p[(size_t)sA * 64 + lane];
            unsigned int kB = k16p[(size_t)sB * 64 + lane];
            unsigned int kC = k16p[(size_t)sC * 64 + lane];
            unsigned int kD = k16p[(size_t)sD * 64 + lane];
            float alA = hA.z * edge_alpha(lane, qq, wd0, wd1, wd2, wd3, tab2, hA.y, dA, kA);
            float alB = hB.z * edge_alpha(lane, qq, wd0, wd1, wd2, wd3, tab2, hB.y, dB, kB);
            float alC = hC.z * edge_alpha(lane, qq, wd0, wd1, wd2, wd3, tab2, hC.y, dC, kC);
            float alD = hD.z * edge_alpha(lane, qq, wd0, wd1, wd2, wd3, tab2, hD.y, dD, kD);
            float adA = __shfl(alA, ssel);
            float adB = __shfl(alB, ssel);
            float adC = __shfl(alC, ssel);
            float adD = __shfl(alD, ssel);
            float ad = (g == 0) ? adA : (g == 1) ? adB : (g == 2) ? adC : adD;
            devacc += ad * Yp[(size_t)(ei + g) * 16 + c];
        }
        for (; ei < e1; ei++) {
            float4 hA = edata[2 * ei], dA = edata[2 * ei + 1];
            int sA = __float_as_int(hA.x);
            unsigned int kA = k16p[(size_t)sA * 64 + lane];
            float alA = hA.z * edge_alpha(lane, qq, wd0, wd1, wd2, wd3, tab2, hA.y, dA, kA);
            float adA = __shfl(alA, ssel);
            if (g == 0) devacc += adA * Yp[(size_t)ei * 16 + c];
        }
        devacc += __shfl_xor(devacc, 16, 64);
        devacc += __shfl_xor(devacc, 32, 64);
        if (lane < 16) outbuf[n * 16 + lane] = devacc;
    }
}

// ---------------------------------------------------------------------------
// Mega-fused exchange + next-t qkv (or readout). 512 threads, ct-half split.
// ---------------------------------------------------------------------------
__global__ __launch_bounds__(512) void exchange_fused_kernel(
    float* __restrict__ f, float* __restrict__ ev, const float* __restrict__ dEv,
    const unsigned int* __restrict__ B1, const float* __restrict__ Wex1,
    const float* __restrict__ bex1,
    const unsigned int* __restrict__ B2, const float* __restrict__ Wex2,
    const float* __restrict__ bex2,
    const unsigned int* __restrict__ Bq, const unsigned int* __restrict__ Bk,
    const unsigned int* __restrict__ Bv,
    float* __restrict__ qout, unsigned int* __restrict__ kvout,
    const float* __restrict__ bo1, const float* __restrict__ Wo2,
    const float* __restrict__ bo2, float* __restrict__ node_e,
    int last, int N)
{
    __shared__ unsigned int sA[64 * APITCH];  // f bf16 -> hid bf16 -> fnew bf16
    __shared__ float sev[64][17];
    __shared__ float sEvInv[64][4];
    __shared__ float sW1x[4][F];
    __shared__ float sW2x[F][4];
    __shared__ float sB1[F];
    __shared__ float sB2[F];
    __shared__ float sb2x[4];
    __shared__ float syb[64][4];
    __shared__ float sRB[F];
    __shared__ float sRW[F];
    __shared__ float spart[64][2];

    int tid = threadIdx.x;
    int n0 = blockIdx.x * 64;
    #pragma unroll
    for (int rep = 0; rep < 8; rep++) {
        int idx = rep * 512 + tid;
        int node = idx >> 6, jj = idx & 63;
        int n = n0 + node;
        float2 v = (n < N) ? ((const float2*)f)[(size_t)n * 64 + jj] : make_float2(0.f, 0.f);
        sA[node * APITCH + jj] = pk_bf2(v.x, v.y);
    }
    for (int idx = tid; idx < 64 * 16; idx += 512) {
        int node = idx >> 4, c = idx & 15;
        int n = n0 + node;
        sev[node][c] = (n < N) ? (ev[(size_t)n * 16 + c] + dEv[(size_t)n * 16 + c]) : 0.0f;
    }
    if (tid < 4 * F)
        sW1x[tid >> 7][tid & 127] = Wex1[(size_t)(128 + (tid >> 7)) * F + (tid & 127)];
    if (tid < F * 4)
        sW2x[tid >> 2][tid & 3] = Wex2[(size_t)(tid >> 2) * (F + 4) + 128 + (tid & 3)];
    if (tid < F) sB1[tid] = bex1[tid];
    else if (tid < 2 * F) sB2[tid - F] = bex2[tid - F];
    if (tid < 4) sb2x[tid] = bex2[F + tid];
    if (last) {
        if (tid < F) sRB[tid] = bo1[tid];
        else if (tid < 2 * F) sRW[tid - F] = Wo2[tid - F];
    }
    __syncthreads();
    if (tid < 256) {
        int node = tid >> 2, d = tid & 3;
        int c0 = (d == 0) ? 0 : (d == 1) ? 1 : (d == 2) ? 4 : 9;
        int c1 = (d == 0) ? 1 : (d == 1) ? 4 : (d == 2) ? 9 : 16;
        float a = 0.0f;
        for (int c = c0; c < c1; c++) { float v = sev[node][c]; a += v * v; }
        sEvInv[node][d] = a;
    }
    int wave = tid >> 6, lane = tid & 63;
    int rg = wave & 3, ch = wave >> 2;
    int quad = lane >> 4, col = lane & 15;
    int mrow = rg * 16 + col;
    s16x8 af[4];
    #pragma unroll
    for (int kb = 0; kb < 4; kb++) {
        FragU fu;
        fu.u = *(const uint4*)&sA[mrow * APITCH + kb * 16 + quad * 4];
        af[kb] = fu.s;
    }
    __syncthreads();
    float evq[4][4];
    #pragma unroll
    for (int r = 0; r < 4; r++) {
        int node = rg * 16 + quad * 4 + r;
        #pragma unroll
        for (int d = 0; d < 4; d++) evq[r][d] = sEvInv[node][d];
    }
    // GEMM1: hid = silu(f@Wex1[:128] + ev_inv@Wex1[128:] + b1) -> sA
    for (int c2 = 0; c2 < 4; c2++) {
        int ct = ch * 4 + c2;
        f32x4 acc = {0.f, 0.f, 0.f, 0.f};
        #pragma unroll
        for (int kb = 0; kb < 4; kb++) {
            FragU bu;
            bu.u = *(const uint4*)&B1[(size_t)((ct * 16 + kb * 4 + quad) * 16 + col) * 4];
            acc = __builtin_amdgcn_mfma_f32_16x16x32_bf16(af[kb], bu.s, acc, 0, 0, 0);
        }
        int j = ct * 16 + col;
        float w0 = sW1x[0][j], w1 = sW1x[1][j], w2 = sW1x[2][j], w3 = sW1x[3][j];
        float bj = sB1[j];
        #pragma unroll
        for (int r = 0; r < 4; r++) {
            float x = acc[r] + bj + evq[r][0] * w0 + evq[r][1] * w1
                    + evq[r][2] * w2 + evq[r][3] * w3;
            float h = silu_f(x);
            float other = __shfl_xor(h, 1, 64);
            if (!(lane & 1)) {
                int node = rg * 16 + quad * 4 + r;
                sA[node * APITCH + ct * 8 + (col >> 1)] = pk_bf2(h, other);
            }
        }
    }
    __syncthreads();
    s16x8 a2[4];
    #pragma unroll
    for (int kb = 0; kb < 4; kb++) {
        FragU fu;
        fu.u = *(const uint4*)&sA[mrow * APITCH + kb * 16 + quad * 4];
        a2[kb] = fu.s;
    }
    // yb2 (cols 128..131) per (node, d) thread — reads sA(hid)
    if (tid < 256) {
        int node = tid >> 2, d = tid & 3;
        float a = sb2x[d];
        for (int dw = 0; dw < 64; dw++) {
            unsigned int u = sA[node * APITCH + dw];
            a += up_lo(u) * sW2x[2 * dw][d] + up_hi(u) * sW2x[2 * dw + 1][d];
        }
        syb[node][d] = a;
    }
    __syncthreads();   // all sA(hid) reads done before overwrite with fnew
    // GEMM2: fnew = f + hid@Wex2[:, :128] + b2 -> write f + pack fnew -> sA
    for (int c2 = 0; c2 < 4; c2++) {
        int ct = ch * 4 + c2;
        f32x4 acc = {0.f, 0.f, 0.f, 0.f};
        #pragma unroll
        for (int kb = 0; kb < 4; kb++) {
            FragU bu;
            bu.u = *(const uint4*)&B2[(size_t)((ct * 16 + kb * 4 + quad) * 16 + col) * 4];
            acc = __builtin_amdgcn_mfma_f32_16x16x32_bf16(a2[kb], bu.s, acc, 0, 0, 0);
        }
        int j = ct * 16 + col;
        float bj = sB2[j];
        #pragma unroll
        for (int r = 0; r < 4; r++) {
            int node = rg * 16 + quad * 4 + r;
            int n = n0 + node;
            float fx = 0.0f;
            if (n < N) {
                size_t ix = (size_t)n * F + j;
                fx = f[ix] + acc[r] + bj;
                f[ix] = fx;
            }
            float other = __shfl_xor(fx, 1, 64);
            if (!(lane & 1)) sA[node * APITCH + ct * 8 + (col >> 1)] = pk_bf2(fx, other);
        }
    }
    __syncthreads();
    // ev update
    for (int idx = tid; idx < 64 * 16; idx += 512) {
        int node = idx >> 4, c = idx & 15;
        int n = n0 + node;
        if (n < N) ev[(size_t)n * 16 + c] = sev[node][c] * (1.0f + syb[node][deg_of(c)]);
    }
    s16x8 a3[4];
    #pragma unroll
    for (int kb = 0; kb < 4; kb++) {
        FragU fu;
        fu.u = *(const uint4*)&sA[mrow * APITCH + kb * 16 + quad * 4];
        a3[kb] = fu.s;
    }
    if (!last) {
        // q = fnew @ Wq[t+1] (fp32)
        for (int c2 = 0; c2 < 4; c2++) {
            int ct = ch * 4 + c2;
            f32x4 acc = {0.f, 0.f, 0.f, 0.f};
            #pragma unroll
            for (int kb = 0; kb < 4; kb++) {
                FragU bu;
                bu.u = *(const uint4*)&Bq[(size_t)((ct * 16 + kb * 4 + quad) * 16 + col) * 4];
                acc = __builtin_amdgcn_mfma_f32_16x16x32_bf16(a3[kb], bu.s, acc, 0, 0, 0);
            }
            #pragma unroll
            for (int r = 0; r < 4; r++) {
                int n = n0 + rg * 16 + quad * 4 + r;
                if (n < N) qout[(size_t)n * F + ct * 16 + col] = acc[r];
            }
        }
        // k and v = fnew @ Wk/Wv (bf16 packed, interleaved kv)
        for (int m = 0; m < 2; m++) {
            const unsigned int* B = (m == 0) ? Bk : Bv;
            for (int c2 = 0; c2 < 4; c2++) {
                int ct = ch * 4 + c2;
                f32x4 acc = {0.f, 0.f, 0.f, 0.f};
                #pragma unroll
                for (int kb = 0; kb < 4; kb++) {
                    FragU bu;
                    bu.u = *(const uint4*)&B[(size_t)((ct * 16 + kb * 4 + quad) * 16 + col) * 4];
                    acc = __builtin_amdgcn_mfma_f32_16x16x32_bf16(a3[kb], bu.s, acc, 0, 0, 0);
                }
                #pragma unroll
                for (int r = 0; r < 4; r++) {
                    float other = __shfl_xor(acc[r], 1, 64);
                    if (!(lane & 1)) {
                        int n = n0 + rg * 16 + quad * 4 + r;
                        if (n < N) {
                            size_t base = (size_t)n * 64 + ct * 8 + (col >> 1);
                            kvout[base * 2 + m] = pk_bf2(acc[r], other);
                        }
                    }
                }
            }
        }
    } else {
        // readout: node_e = silu(fnew@Wo1 + bo1) . Wo2 + bo2 (ct-half partials)
        float part[4] = {0.f, 0.f, 0.f, 0.f};
        for (int c2 = 0; c2 < 4; c2++) {
            int ct = ch * 4 + c2;
            f32x4 acc = {0.f, 0.f, 0.f, 0.f};
            #pragma unroll
            for (int kb = 0; kb < 4; kb++) {
                FragU bu;
                bu.u = *(const uint4*)&Bq[(size_t)((ct * 16 + kb * 4 + quad) * 16 + col) * 4];
                acc = __builtin_amdgcn_mfma_f32_16x16x32_bf16(a3[kb], bu.s, acc, 0, 0, 0);
            }
            int j = ct * 16 + col;
            float bj = sRB[j], wj = sRW[j];
            #pragma unroll
            for (int r = 0; r < 4; r++) part[r] += silu_f(acc[r] + bj) * wj;
        }
        #pragma unroll
        for (int r = 0; r < 4; r++) part[r] = red16_dpp(part[r]);
        if (col == 0) {
            #pragma unroll
            for (int r = 0; r < 4; r++) spart[rg * 16 + quad * 4 + r][ch] = part[r];
        }
        __syncthreads();
        if (tid < 64) {
            int n = n0 + tid;
            if (n < N) node_e[n] = spart[tid][0] + spart[tid][1] + bo2[0];
        }
    }
}

// ---------------------------------------------------------------------------
// energy[g] = sum_{batch[n]==g} node_e[n]
// ---------------------------------------------------------------------------
__global__ __launch_bounds__(256) void energy_reduce_kernel(
    const float* __restrict__ node_e, const int* __restrict__ batch,
    float* __restrict__ energy, int N)
{
    __shared__ float eacc[64];
    if (threadIdx.x < 64) eacc[threadIdx.x] = 0.0f;
    __syncthreads();
    for (int n = blockIdx.x * blockDim.x + threadIdx.x; n < N; n += gridDim.x * blockDim.x)
        atomicAdd(&eacc[batch[n]], node_e[n]);
    __syncthreads();
    if (threadIdx.x < 64) atomicAdd(&energy[threadIdx.x], eacc[threadIdx.x]);
}

// ---------------------------------------------------------------------------
extern "C" void kernel_launch(void* const* d_in, const int* in_sizes, int n_in,
                              void* d_out, int out_size, void* d_ws, size_t ws_size,
                              hipStream_t stream)
{
    const float* positions = (const float*)d_in[0];
    const int*   species   = (const int*)d_in[1];
    const int*   senders   = (const int*)d_in[2];
    const int*   receivers = (const int*)d_in[3];
    const int*   batch     = (const int*)d_in[4];
    const float* embed     = (const float*)d_in[5];
    const float* Wq    = (const float*)d_in[6];
    const float* Wk    = (const float*)d_in[7];
    const float* Wv    = (const float*)d_in[8];
    const float* Wo    = (const float*)d_in[9];
    const float* Wrbf1 = (const float*)d_in[10];
    const float* brbf1 = (const float*)d_in[11];
    const float* Wrbf2 = (const float*)d_in[12];
    const float* Wdeg  = (const float*)d_in[13];
    const float* Wq2   = (const float*)d_in[14];
    const float* Wk2   = (const float*)d_in[15];
    const float* Wex1  = (const float*)d_in[16];
    const float* bex1  = (const float*)d_in[17];
    const float* Wex2  = (const float*)d_in[18];
    const float* bex2  = (const float*)d_in[19];
    const float* Wo1   = (const float*)d_in[20];
    const float* bo1   = (const float*)d_in[21];
    const float* Wo2   = (const float*)d_in[22];
    const float* bo2   = (const float*)d_in[23];

    int N = in_sizes[0] / 3;
    int E = in_sizes[2];

    // ---- workspace layout (~115 MB) ----
    float* ws     = (float*)d_ws;
    float* Yp     = ws;  ws += (size_t)E * 16;        // CSR-ordered Y (30.7 MB)
    float4* edata = (float4*)ws; ws += (size_t)E * 8; // packed edge stream (15.4 MB)
    float* f      = ws;  ws += (size_t)N * F;
    float* evb    = ws;  ws += (size_t)N * 16;
    float* dEv    = ws;  ws += (size_t)N * 16;
    float* q      = ws;  ws += (size_t)N * F;         // doubles as agg
    float* node_e = ws;  ws += (size_t)N;
    float* Cb     = ws;  ws += (size_t)E;             // C only (for ev0)
    uint2* tab2 = (uint2*)ws;  ws += (size_t)TINTER * TAB_N * 64 * 2;
    uint2* kv16 = (uint2*)ws;  ws += (size_t)N * 64 * 2;
    unsigned int* k16p = (unsigned int*)ws;  ws += (size_t)N * 64;
    int* sp    = (int*)ws;  ws += E;
    int* rcvp  = (int*)ws;  ws += E;
    int* cnt   = (int*)ws;  ws += N;
    int* off   = (int*)ws;  ws += N + 1;
    int* cur   = (int*)ws;  ws += N;
    int* elist = (int*)ws;  ws += E;
    int* bsum  = (int*)ws;  ws += 1024;
    int* boff  = (int*)ws;  ws += 1024;
    unsigned int* Wpk  = (unsigned int*)ws;  ws += 18 * 8192;
    unsigned int* Wpk2 = (unsigned int*)ws;  ws += 7 * 8192;

    // ---- CSR build (parallel scan) ----
    int nb = (N + SCB - 1) / SCB;
    hipMemsetAsync(cnt, 0, (size_t)N * sizeof(int), stream);
    count_kernel<<<(E + 255) / 256, 256, 0, stream>>>(receivers, cnt, E);
    scan_part_kernel<<<nb, SCB, 0, stream>>>(cnt, off, bsum, N);
    scan_mid_kernel<<<1, 1024, 0, stream>>>(bsum, boff, off, N, nb);
    scan_add_kernel<<<(N + 255) / 256, 256, 0, stream>>>(off, cur, boff, N);
    scatter_kernel<<<(E + 255) / 256, 256, 0, stream>>>(receivers, cur, elist, E);

    // ---- geometry + packing + table ----
    edge_geom_csr_kernel<<<(E + 255) / 256, 256, 0, stream>>>(elist, positions, senders,
                                                              receivers, sp, rcvp, Cb,
                                                              edata, Yp, E);
    pack_w_kernel<<<(18 * 8192 + 255) / 256, 256, 0, stream>>>(Wq, Wk, Wv, Wo, Wq2, Wk2, Wpk);
    pack_ex_kernel<<<(7 * 8192 + 255) / 256, 256, 0, stream>>>(Wex1, Wex2, Wo1, Wpk2);
    build_table_kernel<<<dim3(TAB_N / 4, TINTER), 256, 0, stream>>>(Wrbf1, brbf1, Wrbf2,
                                                                    (unsigned int*)tab2);
    ev0_kernel<<<(N + 15) / 16, 256, 0, stream>>>(off, Yp, Cb, evb, N);
    embed_kernel<<<N, F, 0, stream>>>(species, embed, f, N);

    int nmb = (N + 63) / 64;
    int npb = (N + 3) / 4;
    int edb = (E + 255) / 256;
    // t=0 qkv
    node_gemm_mfma_kernel<<<nmb, 512, 0, stream>>>(f, Wpk + 0 * 8192, Wpk + 3 * 8192,
                                                   Wpk + 6 * 8192, q, (unsigned int*)kv16, N);
    for (int t = 0; t < TINTER; t++) {
        const unsigned int* Wpk_o  = Wpk + (size_t)(3 * 3 + t) * 8192;
        const unsigned int* Wpk_q2 = Wpk + (size_t)(4 * 3 + t) * 8192;
        const unsigned int* Wpk_k2 = Wpk + (size_t)(5 * 3 + t) * 8192;
        const uint2* tab_t = tab2 + (size_t)t * TAB_N * 64;
        const float* Wdeg_t = Wdeg + (size_t)t * 4 * F;
        int last = (t == TINTER - 1);
        const unsigned int* Bq_n = last ? (Wpk2 + (size_t)6 * 8192)
                                        : (Wpk + (size_t)(0 * 3 + t + 1) * 8192);
        const unsigned int* Bk_n = Wpk + (size_t)(1 * 3 + (last ? t : t + 1)) * 8192;
        const unsigned int* Bv_n = Wpk + (size_t)(2 * 3 + (last ? t : t + 1)) * 8192;

        dd_kernel<<<edb, 256, 0, stream>>>(sp, rcvp, evb, edata, E);
        edge_pass_node_kernel<<<npb, 256, 0, stream>>>(off, edata, Yp,
            q, kv16, nullptr, tab_t, Wdeg_t, q /*agg: aliases qbuf, own-row only*/, N, 0);
        fused_o_qk_kernel<<<nmb, 512, 0, stream>>>(q, Wpk_o, Wpk_q2, Wpk_k2,
                                                   f, q, k16p, N);
        edge_pass_node_kernel<<<npb, 256, 0, stream>>>(off, edata, Yp,
            q, nullptr, k16p, tab_t, Wdeg_t, dEv, N, 1);
        exchange_fused_kernel<<<nmb, 512, 0, stream>>>(f, evb, dEv,
            Wpk2 + (size_t)t * 8192, Wex1 + (size_t)t * (F + 4) * F, bex1 + (size_t)t * F,
            Wpk2 + (size_t)(3 + t) * 8192, Wex2 + (size_t)t * F * (F + 4),
            bex2 + (size_t)t * (F + 4),
            Bq_n, Bk_n, Bv_n, q, (unsigned int*)kv16,
            bo1, Wo2, bo2, node_e, last, N);
    }
    hipMemsetAsync(d_out, 0, (size_t)out_size * sizeof(float), stream);
    energy_reduce_kernel<<<16, 256, 0, stream>>>(node_e, batch, (float*)d_out, N);
}